// Round 1
// baseline (392.621 us; speedup 1.0000x reference)
//
#include <hip/hip_runtime.h>

#define N_NODES_C 50000
#define N_EDGES_C 1600000
#define FDIM 64
#define EPS_C 1e-5f

// ---------------------------------------------------------------------------
// Pass 1: per-node sum, sum-of-squares, degree via segment atomics.
// 16 lanes per edge, float4 per lane (64 floats = one edge row, coalesced).
// ---------------------------------------------------------------------------
__global__ void __launch_bounds__(256)
stats_kernel(const float4* __restrict__ e4, const int* __restrict__ dst,
             float* __restrict__ s, float* __restrict__ ss,
             float* __restrict__ deg, int nEdges) {
    const int total = nEdges * 16;
    const int stride = gridDim.x * blockDim.x;   // multiple of 256 -> group-aligned
    for (int idx = blockIdx.x * blockDim.x + threadIdx.x; idx < total; idx += stride) {
        float4 v = e4[idx];
        float sum = v.x + v.y + v.z + v.w;
        float sq  = v.x * v.x + v.y * v.y + v.z * v.z + v.w * v.w;
        // reduce across the 16-lane group (masks < 16 stay in-group)
        #pragma unroll
        for (int m = 1; m < 16; m <<= 1) {
            sum += __shfl_xor(sum, m);
            sq  += __shfl_xor(sq,  m);
        }
        int sub = idx & 15;
        if (sub < 3) {
            int d = dst[idx >> 4];
            if (sub == 0)      atomicAdd(&s[d],  sum);
            else if (sub == 1) atomicAdd(&ss[d], sq);
            else               atomicAdd(&deg[d], 1.0f);
        }
    }
}

// ---------------------------------------------------------------------------
// Pass 2: per-node mean and 1/(std+eps); unbiased (n-1) variance.
// ---------------------------------------------------------------------------
__global__ void __launch_bounds__(256)
finalize_kernel(const float* __restrict__ s, const float* __restrict__ ss,
                const float* __restrict__ deg, float2* __restrict__ stats,
                int nNodes) {
    int n = blockIdx.x * blockDim.x + threadIdx.x;
    if (n >= nNodes) return;
    float cnt  = deg[n] * (float)FDIM;
    float safe = fmaxf(cnt, 1.0f);
    float mean = s[n] / safe;
    float var  = (ss[n] - cnt * mean * mean) / fmaxf(cnt - 1.0f, 1.0f);
    float stdv = sqrtf(fmaxf(var, 0.0f));
    stats[n] = make_float2(mean, 1.0f / (stdv + EPS_C));
}

// ---------------------------------------------------------------------------
// Pass 3: out = gamma * (e - mean[dst]) * inv[dst] + beta
// ---------------------------------------------------------------------------
__global__ void __launch_bounds__(256)
norm_kernel(const float4* __restrict__ e4, const int* __restrict__ dst,
            const float2* __restrict__ stats,
            const float4* __restrict__ gamma4, const float4* __restrict__ beta4,
            float4* __restrict__ out4, int nEdges) {
    const int total = nEdges * 16;
    const int stride = gridDim.x * blockDim.x;
    const int sub = (blockIdx.x * blockDim.x + threadIdx.x) & 15; // invariant: stride%16==0
    const float4 g = gamma4[sub];
    const float4 b = beta4[sub];
    for (int idx = blockIdx.x * blockDim.x + threadIdx.x; idx < total; idx += stride) {
        float2 mi = stats[dst[idx >> 4]];
        float4 v  = e4[idx];
        float4 o;
        o.x = g.x * (v.x - mi.x) * mi.y + b.x;
        o.y = g.y * (v.y - mi.x) * mi.y + b.y;
        o.z = g.z * (v.z - mi.x) * mi.y + b.z;
        o.w = g.w * (v.w - mi.x) * mi.y + b.w;
        out4[idx] = o;
    }
}

extern "C" void kernel_launch(void* const* d_in, const int* in_sizes, int n_in,
                              void* d_out, int out_size, void* d_ws, size_t ws_size,
                              hipStream_t stream) {
    const float* e     = (const float*)d_in[0];
    const float* gamma = (const float*)d_in[1];
    const float* beta  = (const float*)d_in[2];
    const int*   dst   = (const int*)d_in[3];
    const int nEdges = in_sizes[3];
    const int nNodes = N_NODES_C;

    float* s_acc  = (float*)d_ws;                  // [N]
    float* ss_acc = s_acc + nNodes;                // [N]
    float* deg    = ss_acc + nNodes;               // [N]
    float2* stats = (float2*)(deg + nNodes);       // [N], 8B-aligned (3*N*4 % 8 == 0)

    // zero the atomic accumulators (harness does not re-poison between replays)
    hipMemsetAsync(d_ws, 0, (size_t)3 * nNodes * sizeof(float), stream);

    const int blk = 256;
    const int grid_stream = 2048;                  // 256 CU x 8 blocks, grid-stride
    stats_kernel<<<grid_stream, blk, 0, stream>>>(
        (const float4*)e, dst, s_acc, ss_acc, deg, nEdges);
    finalize_kernel<<<(nNodes + blk - 1) / blk, blk, 0, stream>>>(
        s_acc, ss_acc, deg, stats, nNodes);
    norm_kernel<<<grid_stream, blk, 0, stream>>>(
        (const float4*)e, dst, stats,
        (const float4*)gamma, (const float4*)beta,
        (float4*)d_out, nEdges);
}

// Round 2
// 387.298 us; speedup vs baseline: 1.0137x; 1.0137x over previous
//
#include <hip/hip_runtime.h>

#define N_NODES_C 50000
#define FDIM 64
#define EPS_C 1e-5f
#define NCOPY 8   // one accumulator copy per XCD

__device__ __forceinline__ int xcd_id() {
    int x;
    asm volatile("s_getreg_b32 %0, hwreg(HW_REG_XCC_ID)" : "=s"(x));
    return x & (NCOPY - 1);
}

// Workgroup-scope atomic: executes at the local XCD's TCC (L2); no cross-XCD
// write-through. Safe because each XCD owns a private accumulator copy.
__device__ __forceinline__ void atomic_add_wg(float* p, float v) {
    __hip_atomic_fetch_add(p, v, __ATOMIC_RELAXED, __HIP_MEMORY_SCOPE_WORKGROUP);
}

// ---------------------------------------------------------------------------
// Pass 1: per-node sum / sum-of-squares / degree into per-XCD private copies.
// 16 lanes per edge, float4 per lane (coalesced 1 KB per wave-load).
// ---------------------------------------------------------------------------
__global__ void __launch_bounds__(256)
stats_kernel(const float4* __restrict__ e4, const int* __restrict__ dst,
             float* __restrict__ acc /* [NCOPY][3][N_NODES] */, int nEdges) {
    const int xid = xcd_id();
    float* s_c  = acc + (size_t)xid * 3 * N_NODES_C;
    float* ss_c = s_c + N_NODES_C;
    float* dg_c = ss_c + N_NODES_C;

    const int total = nEdges * 16;
    const int stride = gridDim.x * blockDim.x;   // multiple of 256 -> 16-group aligned
    for (int idx = blockIdx.x * blockDim.x + threadIdx.x; idx < total; idx += stride) {
        float4 v = e4[idx];
        float sum = v.x + v.y + v.z + v.w;
        float sq  = v.x * v.x + v.y * v.y + v.z * v.z + v.w * v.w;
        #pragma unroll
        for (int m = 1; m < 16; m <<= 1) {
            sum += __shfl_xor(sum, m);
            sq  += __shfl_xor(sq,  m);
        }
        int sub = idx & 15;
        if (sub < 3) {
            int d = dst[idx >> 4];
            if (sub == 0)      atomic_add_wg(&s_c[d],  sum);
            else if (sub == 1) atomic_add_wg(&ss_c[d], sq);
            else               atomic_add_wg(&dg_c[d], 1.0f);
        }
    }
}

// ---------------------------------------------------------------------------
// Pass 2: reduce the 8 XCD copies, then mean and 1/(std+eps); unbiased (n-1).
// (end-of-dispatch L2 writeback makes all copies visible here)
// ---------------------------------------------------------------------------
__global__ void __launch_bounds__(256)
finalize_kernel(const float* __restrict__ acc, float2* __restrict__ stats,
                int nNodes) {
    int n = blockIdx.x * blockDim.x + threadIdx.x;
    if (n >= nNodes) return;
    float s = 0.f, q = 0.f, dg = 0.f;
    #pragma unroll
    for (int c = 0; c < NCOPY; ++c) {
        const float* base = acc + (size_t)c * 3 * N_NODES_C;
        s  += base[n];
        q  += base[N_NODES_C + n];
        dg += base[2 * N_NODES_C + n];
    }
    float cnt  = dg * (float)FDIM;
    float safe = fmaxf(cnt, 1.0f);
    float mean = s / safe;
    float var  = (q - cnt * mean * mean) / fmaxf(cnt - 1.0f, 1.0f);
    float stdv = sqrtf(fmaxf(var, 0.0f));
    stats[n] = make_float2(mean, 1.0f / (stdv + EPS_C));
}

// ---------------------------------------------------------------------------
// Pass 3: out = gamma * (e - mean[dst]) * inv[dst] + beta   (at roofline)
// ---------------------------------------------------------------------------
__global__ void __launch_bounds__(256)
norm_kernel(const float4* __restrict__ e4, const int* __restrict__ dst,
            const float2* __restrict__ stats,
            const float4* __restrict__ gamma4, const float4* __restrict__ beta4,
            float4* __restrict__ out4, int nEdges) {
    const int total = nEdges * 16;
    const int stride = gridDim.x * blockDim.x;
    const int sub = (blockIdx.x * blockDim.x + threadIdx.x) & 15; // stride%16==0
    const float4 g = gamma4[sub];
    const float4 b = beta4[sub];
    for (int idx = blockIdx.x * blockDim.x + threadIdx.x; idx < total; idx += stride) {
        float2 mi = stats[dst[idx >> 4]];
        float4 v  = e4[idx];
        float4 o;
        o.x = g.x * (v.x - mi.x) * mi.y + b.x;
        o.y = g.y * (v.y - mi.x) * mi.y + b.y;
        o.z = g.z * (v.z - mi.x) * mi.y + b.z;
        o.w = g.w * (v.w - mi.x) * mi.y + b.w;
        out4[idx] = o;
    }
}

extern "C" void kernel_launch(void* const* d_in, const int* in_sizes, int n_in,
                              void* d_out, int out_size, void* d_ws, size_t ws_size,
                              hipStream_t stream) {
    const float* e     = (const float*)d_in[0];
    const float* gamma = (const float*)d_in[1];
    const float* beta  = (const float*)d_in[2];
    const int*   dst   = (const int*)d_in[3];
    const int nEdges = in_sizes[3];
    const int nNodes = N_NODES_C;

    float* acc    = (float*)d_ws;                                   // [8][3][N]
    float2* stats = (float2*)(acc + (size_t)NCOPY * 3 * nNodes);    // [N]

    // zero the per-XCD accumulators (harness does not re-poison between replays)
    hipMemsetAsync(acc, 0, (size_t)NCOPY * 3 * nNodes * sizeof(float), stream);

    const int blk = 256;
    const int grid_stream = 2048;                  // 256 CU x 8 blocks, grid-stride
    stats_kernel<<<grid_stream, blk, 0, stream>>>(
        (const float4*)e, dst, acc, nEdges);
    finalize_kernel<<<(nNodes + blk - 1) / blk, blk, 0, stream>>>(
        acc, stats, nNodes);
    norm_kernel<<<grid_stream, blk, 0, stream>>>(
        (const float4*)e, dst, stats,
        (const float4*)gamma, (const float4*)beta,
        (float4*)d_out, nEdges);
}

// Round 3
// 383.377 us; speedup vs baseline: 1.0241x; 1.0102x over previous
//
#include <hip/hip_runtime.h>

#define N_NODES_C 50000
#define FDIM 64
#define EPS_C 1e-5f

#define PARTS 12            // node-space partitions
#define NPP 4167            // ceil(50000/12) nodes per partition
#define SLICE (3 * NPP)     // floats per block slice (s, ss, deg) = 12501 -> 50004 B LDS
#define BPERP 64            // blocks per partition
#define STATS_BLK 512

// ---------------------------------------------------------------------------
// Pass 1: per-node sum / sum-of-squares / degree, accumulated in LDS over a
// 4167-node partition; each block flushes to a private d_ws slice (no global
// atomics anywhere). e rows are read exactly once chip-wide; dst is rescanned
// by all 12 partitions (6.4 MB, L3-resident).
// ---------------------------------------------------------------------------
__global__ void __launch_bounds__(STATS_BLK)
stats_kernel(const float4* __restrict__ e4, const int* __restrict__ dst,
             float* __restrict__ acc, int nEdges) {
    __shared__ float sm[SLICE];   // [0..NPP) = s, [NPP..2NPP) = ss, [2NPP..3NPP) = deg
    const int tid = threadIdx.x;
    for (int i = tid; i < SLICE; i += STATS_BLK) sm[i] = 0.0f;
    __syncthreads();

    const int p    = blockIdx.x % PARTS;
    const int b    = blockIdx.x / PARTS;
    const int lo   = p * NPP;
    const int span = min(lo + NPP, N_NODES_C) - lo;

    for (int i = b * STATS_BLK + tid; i < nEdges; i += BPERP * STATS_BLK) {
        int local = dst[i] - lo;
        if (local >= 0 && local < span) {
            const float4* __restrict__ row = e4 + (size_t)i * 16;
            float sum = 0.f, sq = 0.f;
#pragma unroll
            for (int j = 0; j < 16; ++j) {
                float4 v = row[j];
                sum += (v.x + v.y) + (v.z + v.w);
                sq  += (v.x * v.x + v.y * v.y) + (v.z * v.z + v.w * v.w);
            }
            atomicAdd(&sm[local], sum);            // ds_add_f32 (LDS atomic)
            atomicAdd(&sm[NPP + local], sq);
            atomicAdd(&sm[2 * NPP + local], 1.0f);
        }
    }
    __syncthreads();
    float* __restrict__ out = acc + (size_t)blockIdx.x * SLICE;
    for (int i = tid; i < SLICE; i += STATS_BLK) out[i] = sm[i];
}

// ---------------------------------------------------------------------------
// Pass 2: sum the BPERP per-block copies of each partition, then mean and
// 1/(std+eps); unbiased (n-1) variance.
// ---------------------------------------------------------------------------
__global__ void __launch_bounds__(256)
reduce_finalize_kernel(const float* __restrict__ acc, float2* __restrict__ stats,
                       int nNodes) {
    int n = blockIdx.x * blockDim.x + threadIdx.x;
    if (n >= nNodes) return;
    int p = n / NPP, local = n % NPP;
    const float* base = acc + (size_t)p * SLICE + local;  // blockIdx = b*PARTS + p
    float s = 0.f, q = 0.f, dg = 0.f;
#pragma unroll 8
    for (int b = 0; b < BPERP; ++b) {
        const float* a = base + (size_t)b * PARTS * SLICE;
        s  += a[0];
        q  += a[NPP];
        dg += a[2 * NPP];
    }
    float cnt  = dg * (float)FDIM;
    float safe = fmaxf(cnt, 1.0f);
    float mean = s / safe;
    float var  = (q - cnt * mean * mean) / fmaxf(cnt - 1.0f, 1.0f);
    float stdv = sqrtf(fmaxf(var, 0.0f));
    stats[n] = make_float2(mean, 1.0f / (stdv + EPS_C));
}

// ---------------------------------------------------------------------------
// Pass 3: out = gamma * (e - mean[dst]) * inv[dst] + beta   (at roofline)
// ---------------------------------------------------------------------------
__global__ void __launch_bounds__(256)
norm_kernel(const float4* __restrict__ e4, const int* __restrict__ dst,
            const float2* __restrict__ stats,
            const float4* __restrict__ gamma4, const float4* __restrict__ beta4,
            float4* __restrict__ out4, int nEdges) {
    const int total = nEdges * 16;
    const int stride = gridDim.x * blockDim.x;
    const int sub = (blockIdx.x * blockDim.x + threadIdx.x) & 15; // stride%16==0
    const float4 g = gamma4[sub];
    const float4 b = beta4[sub];
    for (int idx = blockIdx.x * blockDim.x + threadIdx.x; idx < total; idx += stride) {
        float2 mi = stats[dst[idx >> 4]];
        float4 v  = e4[idx];
        float4 o;
        o.x = g.x * (v.x - mi.x) * mi.y + b.x;
        o.y = g.y * (v.y - mi.x) * mi.y + b.y;
        o.z = g.z * (v.z - mi.x) * mi.y + b.z;
        o.w = g.w * (v.w - mi.x) * mi.y + b.w;
        out4[idx] = o;
    }
}

extern "C" void kernel_launch(void* const* d_in, const int* in_sizes, int n_in,
                              void* d_out, int out_size, void* d_ws, size_t ws_size,
                              hipStream_t stream) {
    const float* e     = (const float*)d_in[0];
    const float* gamma = (const float*)d_in[1];
    const float* beta  = (const float*)d_in[2];
    const int*   dst   = (const int*)d_in[3];
    const int nEdges = in_sizes[3];
    const int nNodes = N_NODES_C;

    float* acc    = (float*)d_ws;                                   // [PARTS*BPERP][SLICE] = 38.4 MB
    float2* stats = (float2*)(acc + (size_t)PARTS * BPERP * SLICE); // [N]

    // Pass 1: partitioned LDS accumulation (writes every acc element -> no memset)
    stats_kernel<<<PARTS * BPERP, STATS_BLK, 0, stream>>>(
        (const float4*)e, dst, acc, nEdges);

    // Pass 2: cross-block reduce + finalize
    reduce_finalize_kernel<<<(nNodes + 255) / 256, 256, 0, stream>>>(
        acc, stats, nNodes);

    // Pass 3: normalize (roofline-bound)
    const int blk = 256;
    const int grid_stream = 2048;
    norm_kernel<<<grid_stream, blk, 0, stream>>>(
        (const float4*)e, dst, stats,
        (const float4*)gamma, (const float4*)beta,
        (float4*)d_out, nEdges);
}

// Round 4
// 267.186 us; speedup vs baseline: 1.4695x; 1.4349x over previous
//
#include <hip/hip_runtime.h>

#define N_NODES_C 50000
#define FDIM 64
#define EPS_C 1e-5f

#define PARTS 16            // node-space partitions (50000/16 = 3125 exact)
#define NPP 3125            // nodes per partition
#define SLICE (3 * NPP)     // floats per block slice (s, ss, deg) = 9375 -> 37.5 KB
#define BPERP 48            // blocks per partition; grid = 16*48 = 768 = 3/CU
#define CHUNK 2048          // edges scanned per chunk (512 threads x int4)
#define STATS_BLK 512

// ---------------------------------------------------------------------------
// Pass 1: compact-then-process. Per chunk: dense scan of dst -> LDS queue of
// matching edge indices; then 16-lane groups read queued 256B rows at full
// lane efficiency, shfl-reduce, and accumulate into LDS stats. No global
// atomics; e read exactly once chip-wide.
// ---------------------------------------------------------------------------
__global__ void __launch_bounds__(STATS_BLK)
stats_kernel(const float4* __restrict__ e4, const int* __restrict__ dst,
             float* __restrict__ acc, int nEdges) {
    __shared__ float sm[SLICE];
    __shared__ int   queue[CHUNK];
    __shared__ int   cnt;
    const int tid = threadIdx.x;
    for (int i = tid; i < SLICE; i += STATS_BLK) sm[i] = 0.0f;

    const int p     = blockIdx.x / BPERP;
    const int b     = blockIdx.x % BPERP;
    const int lo    = p * NPP;
    const int group = tid >> 4, sub = tid & 15;
    const int nChunks = (nEdges + CHUNK - 1) / CHUNK;

    for (int c = b; c < nChunks; c += BPERP) {
        if (tid == 0) cnt = 0;
        __syncthreads();   // prev process done + sm init + cnt reset visible

        // ---- scan: 4 edges/thread, coalesced int4 ----
        int i0 = c * CHUNK + tid * 4;
        if (i0 + 3 < nEdges) {
            int4 d4 = *(const int4*)(dst + i0);
            if ((unsigned)(d4.x - lo) < NPP) queue[atomicAdd(&cnt, 1)] = i0;
            if ((unsigned)(d4.y - lo) < NPP) queue[atomicAdd(&cnt, 1)] = i0 + 1;
            if ((unsigned)(d4.z - lo) < NPP) queue[atomicAdd(&cnt, 1)] = i0 + 2;
            if ((unsigned)(d4.w - lo) < NPP) queue[atomicAdd(&cnt, 1)] = i0 + 3;
        } else {
            for (int i = i0; i < nEdges; ++i)
                if ((unsigned)(dst[i] - lo) < NPP) queue[atomicAdd(&cnt, 1)] = i;
        }
        __syncthreads();
        const int qn = cnt;

        // ---- process: 32 groups of 16 lanes, 2 rows in flight per group ----
        int q = group;
        for (; q + 32 < qn; q += 64) {
            int ia = queue[q], ib = queue[q + 32];
            int la = dst[ia] - lo, lb = dst[ib] - lo;
            float4 va = e4[(size_t)ia * 16 + sub];
            float4 vb = e4[(size_t)ib * 16 + sub];
            float sa = (va.x + va.y) + (va.z + va.w);
            float qa = (va.x * va.x + va.y * va.y) + (va.z * va.z + va.w * va.w);
            float sb = (vb.x + vb.y) + (vb.z + vb.w);
            float qb = (vb.x * vb.x + vb.y * vb.y) + (vb.z * vb.z + vb.w * vb.w);
#pragma unroll
            for (int m = 1; m < 16; m <<= 1) {
                sa += __shfl_xor(sa, m); qa += __shfl_xor(qa, m);
                sb += __shfl_xor(sb, m); qb += __shfl_xor(qb, m);
            }
            if (sub == 0)      { atomicAdd(&sm[la], sa);           atomicAdd(&sm[lb], sb); }
            else if (sub == 1) { atomicAdd(&sm[NPP + la], qa);     atomicAdd(&sm[NPP + lb], qb); }
            else if (sub == 2) { atomicAdd(&sm[2 * NPP + la], 1.f); atomicAdd(&sm[2 * NPP + lb], 1.f); }
        }
        if (q < qn) {
            int ia = queue[q];
            int la = dst[ia] - lo;
            float4 va = e4[(size_t)ia * 16 + sub];
            float sa = (va.x + va.y) + (va.z + va.w);
            float qa = (va.x * va.x + va.y * va.y) + (va.z * va.z + va.w * va.w);
#pragma unroll
            for (int m = 1; m < 16; m <<= 1) {
                sa += __shfl_xor(sa, m); qa += __shfl_xor(qa, m);
            }
            if (sub == 0)      atomicAdd(&sm[la], sa);
            else if (sub == 1) atomicAdd(&sm[NPP + la], qa);
            else if (sub == 2) atomicAdd(&sm[2 * NPP + la], 1.f);
        }
    }
    __syncthreads();
    float* __restrict__ out = acc + (size_t)blockIdx.x * SLICE;
    for (int i = tid; i < SLICE; i += STATS_BLK) out[i] = sm[i];
}

// ---------------------------------------------------------------------------
// Pass 2: sum the BPERP per-block copies of each partition; mean + 1/(std+eps)
// with unbiased (n-1) variance.
// ---------------------------------------------------------------------------
__global__ void __launch_bounds__(256)
reduce_finalize_kernel(const float* __restrict__ acc, float2* __restrict__ stats,
                       int nNodes) {
    int n = blockIdx.x * blockDim.x + threadIdx.x;
    if (n >= nNodes) return;
    int p = n / NPP, local = n - p * NPP;
    const float* base = acc + (size_t)(p * BPERP) * SLICE + local;
    float s = 0.f, q = 0.f, dg = 0.f;
#pragma unroll 8
    for (int bb = 0; bb < BPERP; ++bb) {
        const float* a = base + (size_t)bb * SLICE;
        s  += a[0];
        q  += a[NPP];
        dg += a[2 * NPP];
    }
    float cnt  = dg * (float)FDIM;
    float safe = fmaxf(cnt, 1.0f);
    float mean = s / safe;
    float var  = (q - cnt * mean * mean) / fmaxf(cnt - 1.0f, 1.0f);
    float stdv = sqrtf(fmaxf(var, 0.0f));
    stats[n] = make_float2(mean, 1.0f / (stdv + EPS_C));
}

// ---------------------------------------------------------------------------
// Pass 3: out = gamma * (e - mean[dst]) * inv[dst] + beta   (at roofline)
// ---------------------------------------------------------------------------
__global__ void __launch_bounds__(256)
norm_kernel(const float4* __restrict__ e4, const int* __restrict__ dst,
            const float2* __restrict__ stats,
            const float4* __restrict__ gamma4, const float4* __restrict__ beta4,
            float4* __restrict__ out4, int nEdges) {
    const int total = nEdges * 16;
    const int stride = gridDim.x * blockDim.x;
    const int sub = (blockIdx.x * blockDim.x + threadIdx.x) & 15; // stride%16==0
    const float4 g = gamma4[sub];
    const float4 b = beta4[sub];
    for (int idx = blockIdx.x * blockDim.x + threadIdx.x; idx < total; idx += stride) {
        float2 mi = stats[dst[idx >> 4]];
        float4 v  = e4[idx];
        float4 o;
        o.x = g.x * (v.x - mi.x) * mi.y + b.x;
        o.y = g.y * (v.y - mi.x) * mi.y + b.y;
        o.z = g.z * (v.z - mi.x) * mi.y + b.z;
        o.w = g.w * (v.w - mi.x) * mi.y + b.w;
        out4[idx] = o;
    }
}

extern "C" void kernel_launch(void* const* d_in, const int* in_sizes, int n_in,
                              void* d_out, int out_size, void* d_ws, size_t ws_size,
                              hipStream_t stream) {
    const float* e     = (const float*)d_in[0];
    const float* gamma = (const float*)d_in[1];
    const float* beta  = (const float*)d_in[2];
    const int*   dst   = (const int*)d_in[3];
    const int nEdges = in_sizes[3];
    const int nNodes = N_NODES_C;

    float* acc    = (float*)d_ws;                                   // [16*48][SLICE] = 28.8 MB
    float2* stats = (float2*)(acc + (size_t)PARTS * BPERP * SLICE); // [N]

    // Pass 1: compact-then-process LDS accumulation (writes all of acc -> no memset)
    stats_kernel<<<PARTS * BPERP, STATS_BLK, 0, stream>>>(
        (const float4*)e, dst, acc, nEdges);

    // Pass 2: cross-block reduce + finalize
    reduce_finalize_kernel<<<(nNodes + 255) / 256, 256, 0, stream>>>(
        acc, stats, nNodes);

    // Pass 3: normalize (roofline-bound)
    norm_kernel<<<2048, 256, 0, stream>>>(
        (const float4*)e, dst, stats,
        (const float4*)gamma, (const float4*)beta,
        (float4*)d_out, nEdges);
}